// Round 5
// baseline (117.283 us; speedup 1.0000x reference)
//
#include <hip/hip_runtime.h>
#include <math.h>

// ---------------------------------------------------------------------------
// HyperbolicInfoNCE on MI355X — Round 11: conflict-free LDS stride (168).
//
// R10 post-mortem: LDS pipeline materialized (LDS=40KB, dur 61.5->48.3us)
// but SQ_LDS_BANK_CONFLICT = 2.62M. Fragment ds_read_b128 at row stride
// 320B: 16B-group = (20*row + c) mod 8, 20 even -> 16 lanes on 2 groups =
// 8-way conflict (2.94x, m136) on the ds_read->MFMA critical path.
//
// R11: pad B row stride to 168 shorts (336B = 21 dwords). 21 mod 8 = 5
// (odd) -> groups (21*row + c) mod 8 cycle all 8 as l16 walks -> 2
// lanes/group = free. Global B padded identically, so a 64-row tile is one
// contiguous 21504B chunk = 21 x 1KB global_load_lds issues (6/5/5/5 per
// wave) -- linear copy, both-sides-consistent, no swizzle (rule #21).
// A stays at stride 160 (register path). LDS 2x21KB=42KB, 3 blocks/CU.
// VALUBusy*dur is still pinned at the 25.6us transcendental floor; this
// round removes the in-phase LDS serialization above it.
// ---------------------------------------------------------------------------

#define BDIM   8192
#define K_IN   129
#define K_PADA 160      // A row stride (shorts), 5*32
#define K_PADB 168      // B row stride (shorts), 336B = 21 dwords (odd mod 8)
#define BK     32
#define NKT    5        // k-tiles of 32 covering k=0..159
#define CTILES 8        // 64-col tiles per block (128 rows x 512 cols)

typedef __bf16  bf16x8 __attribute__((ext_vector_type(8)));
typedef float   f32x4  __attribute__((ext_vector_type(4)));

// ws layout (bytes)
#define OFF_A    0u
#define OFF_B    (BDIM * K_PADA * 2u)                 // 2,621,440
#define OFF_RS   (OFF_B + BDIM * K_PADB * 2u)         // 5,373,952
#define OFF_CP   (OFF_RS + BDIM * 4u)                 // 4 replicas of col sums
#define OFF_DG   (OFF_CP + 4u * BDIM * 4u)

// ---- hardware transcendentals (v_sqrt_f32 / v_log_f32 / v_exp_f32) ----
__device__ __forceinline__ float fast_sqrt(float x) {
#if __has_builtin(__builtin_amdgcn_sqrtf)
    return __builtin_amdgcn_sqrtf(x);
#else
    return sqrtf(x);
#endif
}
__device__ __forceinline__ float fast_log2(float x) {
#if __has_builtin(__builtin_amdgcn_logf)
    return __builtin_amdgcn_logf(x);       // log base 2
#else
    return __log2f(x);
#endif
}
__device__ __forceinline__ float fast_exp2(float x) {
#if __has_builtin(__builtin_amdgcn_exp2f)
    return __builtin_amdgcn_exp2f(x);      // 2^x
#else
    extern "C" __device__ float __ocml_native_exp2_f32(float);
    return __ocml_native_exp2_f32(x);
#endif
}

__device__ __forceinline__ unsigned short f2bf_rne(float f) {
    unsigned int u = __float_as_uint(f);
    u += 0x7FFFu + ((u >> 16) & 1u);   // round-to-nearest-even
    return (unsigned short)(u >> 16);
}

// ---------------------------------------------------------------------------
// Kernel 1: fp32 -> bf16. A: K zero-padded 129->160, metric folded (negate
// col 0). B: K zero-padded 129->168. Also zeroes row_sum + 4 col replicas.
// Grid covers BDIM*K_PADB (the larger array).
// ---------------------------------------------------------------------------
__global__ __launch_bounds__(256) void convert_kernel(
    const float* __restrict__ z1, const float* __restrict__ z2,
    unsigned short* __restrict__ A, unsigned short* __restrict__ B,
    float* __restrict__ rs_cp)
{
    int idx = blockIdx.x * 256 + threadIdx.x;
    if (idx < 5 * BDIM) rs_cp[idx] = 0.f;
    if (idx < BDIM * K_PADB) {
        int r = idx / K_PADB;
        int c = idx - r * K_PADB;
        float vb = (c < K_IN) ? z2[r * K_IN + c] : 0.f;
        B[idx] = f2bf_rne(vb);
    }
    if (idx < BDIM * K_PADA) {
        int r = idx / K_PADA;
        int c = idx - r * K_PADA;
        float va = 0.f;
        if (c < K_IN) {
            va = z1[r * K_IN + c];
            if (c == 0) va = -va;      // Lorentz metric on first coordinate
        }
        A[idx] = f2bf_rne(va);
    }
}

// ---------------------------------------------------------------------------
// Kernel 2: strip-GEMM with fused acosh/exp epilogue; B staged through a
// double-buffered LDS pipeline (global_load_lds, T3 minimum recipe).
//   grid = 1024: bid = chunk*64 + strip  (consecutive blocks share B-chunk)
//   block: rows [strip*128, +128) x cols [chunk*512, +512)
//   wave w (0..3): rows [strip*128 + w*32, +32), 8 col-tiles of 64
//   fragment layouts (guide-verified, m89/m91):
//     A/B operand: elem [m=lane&15][k=(lane>>4)*8 + j]
//     C/D:         elem [row=(lane>>4)*4 + reg][col=lane&15]
// ---------------------------------------------------------------------------

#define TILE_BYTES (64 * K_PADB * 2)   // 21504 = 21 KB-issues

// Stage one 64-col B-tile (contiguous 21504B global chunk) into Bs[bufidx].
// 21 x 1KB issues distributed 6/5/5/5 over the 4 waves. LDS dest is
// wave-uniform; HW adds lane*16 (m104). Pure linear byte copy.
#define STAGE(bufidx, cb)                                                     \
    {                                                                         \
        const char* _gp = (const char*)(B + (size_t)(cb) * K_PADB)            \
                          + lane * 16;                                        \
        char* _lp = (char*)&Bs[bufidx][0];                                    \
        for (int _m = wave; _m < 21; _m += 4)                                 \
            __builtin_amdgcn_global_load_lds(                                 \
                (const __attribute__((address_space(1))) void*)               \
                    (_gp + _m * 1024),                                        \
                (__attribute__((address_space(3))) void*)(_lp + _m * 1024),   \
                16, 0, 0);                                                    \
    }

// MFMA + fused epilogue for one 32x64 wave-tile read from Bs[bufidx].
#define COMPUTE(bufidx, cb)                                                   \
    {                                                                         \
        const int colBase = (cb);                                             \
        const unsigned short* _Bt = &Bs[bufidx][0];                           \
        f32x4 acc[2][4] = {};                                                 \
        _Pragma("unroll")                                                     \
        for (int kt = 0; kt < NKT; ++kt) {                                    \
            bf16x8 bfr[4];                                                    \
            _Pragma("unroll")                                                 \
            for (int j = 0; j < 4; ++j)                                       \
                bfr[j] = *(const bf16x8*)                                     \
                    &_Bt[(l16 + j * 16) * K_PADB + quad * 8 + kt * BK];       \
            _Pragma("unroll")                                                 \
            for (int i = 0; i < 2; ++i)                                       \
                _Pragma("unroll")                                             \
                for (int j = 0; j < 4; ++j)                                   \
                    acc[i][j] = __builtin_amdgcn_mfma_f32_16x16x32_bf16(      \
                        Ah[i][kt], bfr[j], acc[i][j], 0, 0, 0);               \
        }                                                                     \
        const bool diagTile = (colBase == (rowBase & ~63));                   \
        const int  dj       = (rowBase >> 4) & 2;                             \
        float colp[4] = {0.f, 0.f, 0.f, 0.f};                                 \
        _Pragma("unroll")                                                     \
        for (int i = 0; i < 2; ++i) {                                         \
            _Pragma("unroll")                                                 \
            for (int j = 0; j < 4; ++j) {                                     \
                _Pragma("unroll")                                             \
                for (int reg = 0; reg < 4; ++reg) {                           \
                    float inner = acc[i][j][reg];                             \
                    float x = fmaxf(-inner, 1.000001f);                       \
                    float s = fast_sqrt(__builtin_fmaf(x, x, -1.0f));         \
                    float l2u = fast_log2(x + s);                             \
                    float e = fast_exp2(-14.285714285714286f * l2u);          \
                    rowp[i][reg] += e;                                        \
                    colp[j]      += e;                                        \
                    if (diagTile && (j - i) == dj && (quad * 4 + reg) == l16){\
                        int R = rowBase + i * 16 + quad * 4 + reg;            \
                        diag[R] = -9.902102579427789f * l2u;                  \
                    }                                                         \
                }                                                             \
            }                                                                 \
        }                                                                     \
        _Pragma("unroll")                                                     \
        for (int j = 0; j < 4; ++j) {                                         \
            float v = colp[j];                                                \
            v += __shfl_xor(v, 16);                                           \
            v += __shfl_xor(v, 32);                                           \
            if (quad == 0)                                                    \
                atomicAdd(&colRep[colBase + j * 16 + l16], v);                \
        }                                                                     \
    }

__global__ __launch_bounds__(256, 3) void gemm_epilogue_kernel(
    const unsigned short* __restrict__ A, const unsigned short* __restrict__ B,
    float* __restrict__ row_sum, float* __restrict__ col_part,
    float* __restrict__ diag)
{
    const int t    = threadIdx.x;
    const int lane = t & 63;
    const int wave = t >> 6;
    const int quad = lane >> 4;
    const int l16  = lane & 15;

    const int strip = blockIdx.x & 63;
    const int chunk = blockIdx.x >> 6;
    const int rowBase  = strip * 128 + wave * 32;   // wave's first row
    const int colChunk = chunk * 512;               // block's first col

    const unsigned short* Abase = A + (rowBase + l16) * K_PADA + quad * 8;
    float* colRep = col_part + (strip & 3) * BDIM;  // contention / 4

    // B-tile double buffer: [64 cols][168 k] linear (byte-for-byte copy of
    // the contiguous global chunk). Row stride 336B -> conflict-free b128.
    __shared__ __align__(16) unsigned short Bs[2][64 * K_PADB];

    // ---- hoist the entire A operand for this wave: 2 row-frags x 5 k-tiles
    bf16x8 Ah[2][NKT];
    #pragma unroll
    for (int i = 0; i < 2; ++i)
        #pragma unroll
        for (int kt = 0; kt < NKT; ++kt)
            Ah[i][kt] = *(const bf16x8*)(Abase + i * 16 * K_PADA + kt * BK);

    float rowp[2][4] = {};   // persistent across all col-tiles

    // ---- 2-phase pipeline: stage next tile, compute current, one barrier
    STAGE(0, colChunk);                  // prologue: tile 0 -> Bs[0]
    __syncthreads();

    #pragma unroll 1
    for (int ct = 0; ct < CTILES; ++ct) {
        if (ct + 1 < CTILES)
            STAGE((ct + 1) & 1, colChunk + (ct + 1) * 64);
        COMPUTE(ct & 1, colChunk + ct * 64);
        __syncthreads();                 // vmcnt(0)+barrier: loads long done
    }

    // row sums: accumulated over all 8 col-tiles; reduce across the 16
    // lanes of each quad (they hold the cols), one atomic per row
    #pragma unroll
    for (int i = 0; i < 2; ++i) {
        #pragma unroll
        for (int reg = 0; reg < 4; ++reg) {
            float v = rowp[i][reg];
            v += __shfl_xor(v, 1);
            v += __shfl_xor(v, 2);
            v += __shfl_xor(v, 4);
            v += __shfl_xor(v, 8);
            if (l16 == 0)
                atomicAdd(&row_sum[rowBase + i * 16 + quad * 4 + reg], v);
        }
    }
}

// ---------------------------------------------------------------------------
// Kernel 3: loss = mean_b( 0.5*(ln rs[b] + ln cs[b]) - diag[b] ),
// cs[b] = sum of 4 replicas.
// ---------------------------------------------------------------------------
__global__ __launch_bounds__(1024) void finalize_kernel(
    const float* __restrict__ rs, const float* __restrict__ cp,
    const float* __restrict__ dg, float* __restrict__ out)
{
    __shared__ float part[16];
    int t = threadIdx.x;
    float a = 0.f;
    const float LN2_HALF = 0.34657359027997264f;  // 0.5 * ln2
    for (int b = t; b < BDIM; b += 1024) {
        float cs = cp[b] + cp[b + BDIM] + cp[b + 2 * BDIM] + cp[b + 3 * BDIM];
        a += LN2_HALF * (fast_log2(rs[b]) + fast_log2(cs)) - dg[b];
    }
    #pragma unroll
    for (int m = 1; m < 64; m <<= 1) a += __shfl_xor(a, m);
    if ((t & 63) == 0) part[t >> 6] = a;
    __syncthreads();
    if (t < 16) {
        float v = part[t];
        #pragma unroll
        for (int m = 1; m < 16; m <<= 1) v += __shfl_xor(v, m);
        if (t == 0) out[0] = v * (1.0f / (float)BDIM);
    }
}

// ---------------------------------------------------------------------------
extern "C" void kernel_launch(void* const* d_in, const int* in_sizes, int n_in,
                              void* d_out, int out_size, void* d_ws, size_t ws_size,
                              hipStream_t stream)
{
    const float* z1 = (const float*)d_in[0];
    const float* z2 = (const float*)d_in[1];
    float* out = (float*)d_out;

    char* ws = (char*)d_ws;
    unsigned short* A  = (unsigned short*)(ws + OFF_A);
    unsigned short* B  = (unsigned short*)(ws + OFF_B);
    float* row_sum     = (float*)(ws + OFF_RS);
    float* col_part    = (float*)(ws + OFF_CP);
    float* diag        = (float*)(ws + OFF_DG);

    convert_kernel<<<(BDIM * K_PADB + 255) / 256, 256, 0, stream>>>(
        z1, z2, A, B, row_sum /* rs + 4 col replicas contiguous */);

    gemm_epilogue_kernel<<<1024, 256, 0, stream>>>(
        A, B, row_sum, col_part, diag);

    finalize_kernel<<<1, 1024, 0, stream>>>(row_sum, col_part, diag, out);
}